// Round 10
// baseline (508.757 us; speedup 1.0000x reference)
//
#include <hip/hip_runtime.h>
#include <cfloat>

// E8 codebook quantize: per row of X[N][8]
//   neg mask, parity -> X_part = |X| with coord0 sign-fixed
//   scores = 2*dot - norm, argmax (first-max), vals/idx via sign-unflip + gather
//
// GOLDEN SCORING CHAIN (verified absmax=0 in R8/R9 — DO NOT CHANGE):
//   p_i = fl(x_i * g_i)            (separately rounded muls)
//   q_i = fl(p_i + p_{i+4})        (stride-4 fold)
//   d   = fl(fl(q0+q1) + fl(q2+q3))
//   s   = fl(2d - n)  == fmaf(2,d,-n) since 2d is exact
//
// R10: packed-FP32 formulation. Pairs are laid out so each v_pk op computes
// two golden-chain ops with IDENTICAL per-component IEEE rounding:
//   P01=(p0,p1)=X01*G01 ... P67=(p6,p7)=X67*G67        (4x v_pk_mul_f32)
//   Q01=(q0,q1)=P01+P45 ; Q23=(q2,q3)=P23+P67          (2x v_pk_add_f32)
//   t0=q0+q1 ; t1=q2+q3 ; d=t0+t1                      (3x v_add_f32)
// 19 -> 13 VALU insts/codeword (floor ~190us -> ~130us).
// Codebook reads remain wave-uniform -> s_load scalar path (R9 win, kept).
//
// Output d_out (float*): vals [N*8] then real_idx [N] (int stored as float).
// allcombo/idx_map are int32-canonicalized on device (established R1-R3).

typedef float f32x2 __attribute__((ext_vector_type(2)));

__global__ __launch_bounds__(256, 4)
void e8_quant_kernel(const float* __restrict__ X,
                     const float* __restrict__ grid_part,   // [P*8] f32
                     const float* __restrict__ grid_norm,   // [P]   f32
                     const int*   __restrict__ allcombo,    // [128*P] int32
                     const int*   __restrict__ idx_map,     // [256] int32
                     float* __restrict__ out,               // [N*8 + N]
                     int N, int P)
{
    #pragma clang fp contract(off)

    int row = blockIdx.x * blockDim.x + threadIdx.x;
    if (row >= N) return;

    const float4* xr = reinterpret_cast<const float4*>(X + (size_t)row * 8);
    float4 xa = xr[0];
    float4 xb = xr[1];
    float x[8] = { xa.x, xa.y, xa.z, xa.w, xb.x, xb.y, xb.z, xb.w };

    // neg mask + parity
    unsigned nm = 0u;
    #pragma unroll
    for (int c = 0; c < 8; ++c) nm |= (x[c] < 0.0f) ? (1u << c) : 0u;
    unsigned odd = __popc(nm) & 1u;

    // X_part = |x|, coord0 negated when parity odd (exact sign ops)
    float xp0 = fabsf(x[0]);
    xp0 = odd ? -xp0 : xp0;

    // adjacent pairs for packed math
    f32x2 X01 = { xp0,           fabsf(x[1]) };
    f32x2 X23 = { fabsf(x[2]),   fabsf(x[3]) };
    f32x2 X45 = { fabsf(x[4]),   fabsf(x[5]) };
    f32x2 X67 = { fabsf(x[6]),   fabsf(x[7]) };

    // argmax over codebook: golden chain in packed form, first-max via strict >
    const f32x2* gp2 = reinterpret_cast<const f32x2*>(grid_part);
    float best = -FLT_MAX;
    int   bidx = 0;
    #pragma unroll 4
    for (int p = 0; p < P; ++p) {
        f32x2 G01 = gp2[4 * p + 0];
        f32x2 G23 = gp2[4 * p + 1];
        f32x2 G45 = gp2[4 * p + 2];
        f32x2 G67 = gp2[4 * p + 3];
        float nrm = grid_norm[p];
        // separately-rounded products (per-component IEEE mul)
        f32x2 P01 = X01 * G01;
        f32x2 P23 = X23 * G23;
        f32x2 P45 = X45 * G45;
        f32x2 P67 = X67 * G67;
        // stride-4 fold: (q0,q1) and (q2,q3)
        f32x2 Q01 = P01 + P45;
        f32x2 Q23 = P23 + P67;
        // adjacent merge
        float t0 = Q01.x + Q01.y;
        float t1 = Q23.x + Q23.y;
        float d  = t0 + t1;
        // s = fl(2d - n): 2d exact, single rounding == fl(fl(2d)-n)
        float s  = fmaf(2.0f, d, -nrm);
        bool gt = (s > best);
        best = gt ? s : best;
        bidx = gt ? p : bidx;
    }

    // packed sign bits: bit c = neg[c] for c>=1, bit0 = neg0 ^ parity
    unsigned packed = (nm & 0xFEu) | ((nm ^ odd) & 1u);

    // vals = grid_part[best] * mask (exact sign flips)
    const float* g = grid_part + (size_t)bidx * 8;
    float v[8];
    #pragma unroll
    for (int c = 0; c < 8; ++c) {
        float gv = g[c];
        v[c] = ((packed >> c) & 1u) ? -gv : gv;
    }
    float4* orow = reinterpret_cast<float4*>(out + (size_t)row * 8);
    float4 o0 = { v[0], v[1], v[2], v[3] };
    float4 o1 = { v[4], v[5], v[6], v[7] };
    orow[0] = o0;
    orow[1] = o1;

    // real_idx = allcombo[idx_map[packed]][best]
    int crow = idx_map[packed];
    int idxv = allcombo[(size_t)crow * P + bidx];
    out[(size_t)N * 8 + row] = (float)idxv;
}

extern "C" void kernel_launch(void* const* d_in, const int* in_sizes, int n_in,
                              void* d_out, int out_size, void* d_ws, size_t ws_size,
                              hipStream_t stream) {
    const float* X        = (const float*)d_in[0];
    const float* gridpart = (const float*)d_in[1];
    const float* gridnorm = (const float*)d_in[2];
    // d_in[3] = int_map (2^c) — hardcoded as bit shifts
    const int*   allcombo = (const int*)d_in[4];
    const int*   idxmap   = (const int*)d_in[5];
    float* out = (float*)d_out;

    int N = in_sizes[0] / 8;
    int P = in_sizes[2];

    int block = 256;
    int grid  = (N + block - 1) / block;

    hipLaunchKernelGGL(e8_quant_kernel, dim3(grid), dim3(block), 0, stream,
                       X, gridpart, gridnorm, allcombo, idxmap, out, N, P);
}